// Round 3
// baseline (389.901 us; speedup 1.0000x reference)
//
#include <hip/hip_runtime.h>
#include <hip/hip_bf16.h>

// DynamicGATLayer on MI355X — R3: fully-fused MFMA flash-GAT (2 kernels).
// B=2, N=2048, F=128, FE=8, H=4, C=64, HC=256.
//
// Simplifications (verified passing R1/R2):
//  - A * sigmoid(E.W_edge+b) == 0  <=>  A == 0 (sigmoid in (0.1,0.9)), so
//    E/W_edge/b_edge are never read.
//  - |leaky(ss+sd)| <~ 6 -> exp without max-subtraction is safe in fp32;
//    masked entries are exactly 0 both here and in the reference.
//  - ss/sd pre-scaled by log2(e): exp(leaky(x)) = exp2(leaky(x*log2e)).
//
// R3 structure:
//  K1: h = X.Wgat (fp32), emit hT bf16 [b][h][c][n] (n contiguous = MFMA
//      B-frag is one 16B load), ss/sd scaled by log2e.  (unchanged)
//  K2: 256 blocks x 512 thr. Block = (b, 16-row i-tile). Wave w: head w&3,
//      j-half w>>2 (1024 j each). Per 32-j step: Adj float4 loads -> p
//      (exp2, exact-0 mask) -> packed bf16 A-frag; hT B-frags; 4x
//      mfma_f32_16x16x32_bf16; fp32 row sums. j-half partials combined in
//      LDS, then fused softmax-divide + bias + ELU + LayerNorm epilogue.
//      No partial-acc HBM round-trip, no third kernel.

#define BB 2
#define NN 2048
#define FF 128
#define HH 4
#define CC 64
#define HC 256
#define TN 8      // node rows per block, K1
#define LOG2E 1.4426950408889634f

typedef __attribute__((ext_vector_type(8))) short short8;
typedef __attribute__((ext_vector_type(4))) float f32x4;

__device__ __forceinline__ float wave_sum(float v) {
#pragma unroll
    for (int m = 32; m >= 1; m >>= 1) v += __shfl_xor(v, m, 64);
    return v;
}

__device__ __forceinline__ unsigned short bf16rne(float x) {
    unsigned u = __float_as_uint(x);
    return (unsigned short)((u + 0x7fffu + ((u >> 16) & 1u)) >> 16);
}

// ---------------- K1 ----------------
__global__ __launch_bounds__(256) void k1_proj(
    const float* __restrict__ X, const float* __restrict__ Wg,
    const float* __restrict__ a_src, const float* __restrict__ a_dst,
    unsigned short* __restrict__ hT, float* __restrict__ ssT,
    float* __restrict__ sdT)
{
    __shared__ float sX[TN][FF];
    const int blk = blockIdx.x;               // B*N/TN blocks
    const int b  = blk / (NN / TN);
    const int n0 = (blk % (NN / TN)) * TN;
    const int tid = threadIdx.x;
    const int h = tid >> 6, c = tid & 63;

    for (int idx = tid; idx < TN * FF; idx += 256) {
        int r = idx >> 7, f = idx & 127;
        sX[r][f] = X[(size_t)(b * NN + n0 + r) * FF + f];
    }
    __syncthreads();

    float hv[TN];
#pragma unroll
    for (int r = 0; r < TN; ++r) hv[r] = 0.f;

#pragma unroll 4
    for (int f4 = 0; f4 < FF / 4; ++f4) {
        const int f = f4 * 4;
        const float w0 = Wg[(h * FF + f + 0) * CC + c];
        const float w1 = Wg[(h * FF + f + 1) * CC + c];
        const float w2 = Wg[(h * FF + f + 2) * CC + c];
        const float w3 = Wg[(h * FF + f + 3) * CC + c];
#pragma unroll
        for (int r = 0; r < TN; ++r) {
            float4 x4 = *(const float4*)&sX[r][f];
            hv[r] = fmaf(x4.x, w0, hv[r]);
            hv[r] = fmaf(x4.y, w1, hv[r]);
            hv[r] = fmaf(x4.z, w2, hv[r]);
            hv[r] = fmaf(x4.w, w3, hv[r]);
        }
    }

    // hT[b][h][c][n], 8 consecutive n per thread -> one 16B store
    union { short8 v; unsigned short u[8]; } pk;
#pragma unroll
    for (int r = 0; r < TN; ++r) pk.u[r] = bf16rne(hv[r]);
    *(short8*)&hT[((size_t)(b * HH + h) * CC + c) * NN + n0] = pk.v;

    const float as = a_src[tid];
    const float ad = a_dst[tid];
#pragma unroll
    for (int r = 0; r < TN; ++r) {
        const int n = n0 + r;
        float s1 = wave_sum(hv[r] * as);
        float s2 = wave_sum(hv[r] * ad);
        if (c == 0) {
            ssT[(b * HH + h) * NN + n] = s1 * LOG2E;
            sdT[(b * HH + h) * NN + n] = s2 * LOG2E;
        }
    }
}

// ---------------- K2 ----------------
__device__ __forceinline__ short8 make_p(float ss, const float4& sda, const float4& sdb,
                                         const float4& aa, const float4& ab, float& lsum)
{
    const float sd[8] = {sda.x, sda.y, sda.z, sda.w, sdb.x, sdb.y, sdb.z, sdb.w};
    const float av[8] = {aa.x, aa.y, aa.z, aa.w, ab.x, ab.y, ab.z, ab.w};
    float p[8];
#pragma unroll
    for (int t = 0; t < 8; ++t) {
        float x = ss + sd[t];
        x = fmaxf(x, 0.2f * x);                 // leaky_relu (alpha=0.2)
        float pv = (av[t] == 0.f) ? 0.f : __builtin_amdgcn_exp2f(x);
        lsum += pv;
        p[t] = pv;
    }
    union { short8 v; __hip_bfloat162 h2[4]; } pk;
#pragma unroll
    for (int t = 0; t < 4; ++t)
        pk.h2[t] = __float22bfloat162_rn(make_float2(p[2 * t], p[2 * t + 1]));
    return pk.v;
}

__global__ __launch_bounds__(512) void k2_attn(
    const float* __restrict__ Adj, const unsigned short* __restrict__ hT,
    const float* __restrict__ ssT, const float* __restrict__ sdT,
    const float* __restrict__ b_gat, const float* __restrict__ gamma,
    const float* __restrict__ beta, float* __restrict__ out)
{
    __shared__ float accs[16][HH][64];     // 16 KB, bank = lane%32: conflict-free
    __shared__ float lsumx[HH][16];
    __shared__ float red1s[HH][16], red2s[HH][16];

    const int blk = blockIdx.x;            // B * (N/16)
    const int b  = blk >> 7;
    const int i0 = (blk & 127) << 4;
    const int tid  = threadIdx.x;
    const int wave = tid >> 6;
    const int h  = wave & 3;
    const int jh = wave >> 2;              // j-half: [0,1024) or [1024,2048)
    const int l  = tid & 63;
    const int lr = l & 15;                 // A row / B,D col in tile
    const int lq = l >> 4;                 // quad

    const float ss = ssT[(b * HH + h) * NN + i0 + lr];

    f32x4 acc[4];
#pragma unroll
    for (int ni = 0; ni < 4; ++ni) acc[ni] = (f32x4){0.f, 0.f, 0.f, 0.f};
    float lsum = 0.f;

    const float* adjp = Adj + (size_t)(b * NN + i0 + lr) * NN + jh * 1024 + lq * 8;
    const float* sdp  = sdT + (b * HH + h) * NN + jh * 1024 + lq * 8;
    const unsigned short* hb[4];
#pragma unroll
    for (int ni = 0; ni < 4; ++ni)
        hb[ni] = hT + ((size_t)(b * HH + h) * CC + ni * 16 + lr) * NN + jh * 1024 + lq * 8;

    for (int js = 0; js < 1024; js += 32) {
        const float4 aa  = *(const float4*)(adjp + js);
        const float4 ab  = *(const float4*)(adjp + js + 4);
        const float4 sda = *(const float4*)(sdp + js);
        const float4 sdb = *(const float4*)(sdp + js + 4);
        short8 bfr[4];
#pragma unroll
        for (int ni = 0; ni < 4; ++ni) bfr[ni] = *(const short8*)(hb[ni] + js);

        const short8 pa = make_p(ss, sda, sdb, aa, ab, lsum);
#pragma unroll
        for (int ni = 0; ni < 4; ++ni)
            acc[ni] = __builtin_amdgcn_mfma_f32_16x16x32_bf16(pa, bfr[ni], acc[ni], 0, 0, 0);
    }

    // reduce lsum over quads: every lane then holds row-lsum for row lr (this j-half)
    lsum += __shfl_xor(lsum, 16, 64);
    lsum += __shfl_xor(lsum, 32, 64);

    if (jh == 1) {
        if (lq == 0) lsumx[h][lr] = lsum;
#pragma unroll
        for (int ni = 0; ni < 4; ++ni)
#pragma unroll
            for (int r = 0; r < 4; ++r)
                accs[ni * 4 + r][h][l] = acc[ni][r];
    }
    __syncthreads();

    float vals[4][4];   // [ni][r]
    float s1[4], s2[4]; // per acc-row r = lq*4+r (jh==0 only)
    if (jh == 0) {
        const float lcomb = lsum + lsumx[h][lr];   // full-row denominator, row lr
        float lrow[4];
#pragma unroll
        for (int r = 0; r < 4; ++r) lrow[r] = __shfl(lcomb, lq * 4 + r, 64);

        float bg[4];
#pragma unroll
        for (int ni = 0; ni < 4; ++ni) bg[ni] = b_gat[h * 64 + ni * 16 + lr];

#pragma unroll
        for (int r = 0; r < 4; ++r) { s1[r] = 0.f; s2[r] = 0.f; }
#pragma unroll
        for (int ni = 0; ni < 4; ++ni)
#pragma unroll
            for (int r = 0; r < 4; ++r) {
                float a = acc[ni][r] + accs[ni * 4 + r][h][l];
                float v = a / lrow[r] + bg[ni];
                v = (v > 0.f) ? v : (__expf(v) - 1.f);   // ELU
                vals[ni][r] = v;
                s1[r] += v;
                s2[r] += v * v;
            }
        // reduce over the 16 col-lanes of the quad (rows are per-quad)
#pragma unroll
        for (int m = 1; m <= 8; m <<= 1) {
#pragma unroll
            for (int r = 0; r < 4; ++r) {
                s1[r] += __shfl_xor(s1[r], m, 64);
                s2[r] += __shfl_xor(s2[r], m, 64);
            }
        }
        if (lr == 0) {
#pragma unroll
            for (int r = 0; r < 4; ++r) {
                red1s[h][lq * 4 + r] = s1[r];
                red2s[h][lq * 4 + r] = s2[r];
            }
        }
    }
    __syncthreads();

    if (jh == 0) {
        const float g = gamma[h * 64 + lr], g1 = gamma[h * 64 + 16 + lr],
                    g2 = gamma[h * 64 + 32 + lr], g3 = gamma[h * 64 + 48 + lr];
        const float bt = beta[h * 64 + lr], bt1 = beta[h * 64 + 16 + lr],
                    bt2 = beta[h * 64 + 32 + lr], bt3 = beta[h * 64 + 48 + lr];
        const float gm[4] = {g, g1, g2, g3};
        const float bm[4] = {bt, bt1, bt2, bt3};
#pragma unroll
        for (int r = 0; r < 4; ++r) {
            const int row = lq * 4 + r;
            float S1 = red1s[0][row] + red1s[1][row] + red1s[2][row] + red1s[3][row];
            float S2 = red2s[0][row] + red2s[1][row] + red2s[2][row] + red2s[3][row];
            float mu  = S1 * (1.f / HC);
            float var = S2 * (1.f / HC) - mu * mu;
            float inv = rsqrtf(var + 1e-3f);
            float* op = out + (size_t)(b * NN + i0 + row) * HC + h * 64 + lr;
#pragma unroll
            for (int ni = 0; ni < 4; ++ni)
                op[ni * 16] = (vals[ni][r] - mu) * inv * gm[ni] + bm[ni];
        }
    }
}

extern "C" void kernel_launch(void* const* d_in, const int* in_sizes, int n_in,
                              void* d_out, int out_size, void* d_ws, size_t ws_size,
                              hipStream_t stream)
{
    const float* X     = (const float*)d_in[0];
    const float* Adj   = (const float*)d_in[1];
    // d_in[2..4] = E, W_edge, b_edge: unused (see header).
    const float* Wg    = (const float*)d_in[5];
    const float* a_src = (const float*)d_in[6];
    const float* a_dst = (const float*)d_in[7];
    const float* b_gat = (const float*)d_in[8];
    const float* gam   = (const float*)d_in[9];
    const float* bet   = (const float*)d_in[10];
    float* out = (float*)d_out;

    const size_t hT_elems = (size_t)BB * HH * CC * NN;   // ushort (2 MB)
    const size_t ss_elems = (size_t)BB * HH * NN;        // float

    unsigned short* hT = (unsigned short*)d_ws;
    float* ssT = (float*)(hT + hT_elems);
    float* sdT = ssT + ss_elems;

    k1_proj<<<BB * NN / TN, 256, 0, stream>>>(X, Wg, a_src, a_dst, hT, ssT, sdT);
    k2_attn<<<BB * (NN / 16), 512, 0, stream>>>(Adj, hT, ssT, sdT, b_gat, gam, bet, out);
}

// Round 4
// 387.820 us; speedup vs baseline: 1.0054x; 1.0054x over previous
//
#include <hip/hip_runtime.h>
#include <hip/hip_bf16.h>

// DynamicGATLayer on MI355X — R4: fused flash-GAT, latency-optimized K2.
// B=2, N=2048, F=128, FE=8, H=4, C=64, HC=256.
//
// Simplifications (verified passing R1-R3):
//  - A * sigmoid(E.W_edge+b) == 0  <=>  A == 0 (sigmoid in (0.1,0.9)), so
//    E/W_edge/b_edge are never read.
//  - |leaky(ss+sd)| <~ 6 -> exp without max-subtraction is safe in fp32;
//    masked entries are exactly 0 both here and in the reference.
//  - ss/sd pre-scaled by log2(e): exp(leaky(x)) = exp2(leaky(x*log2e)).
//
// R4 deltas vs R3 (which was latency-bound at 2 waves/SIMD, no prefetch):
//  - K2 blocks are 1024 threads: 16 waves = 4 heads x 4 j-quarters
//    (512 j each) -> 4 waves/SIMD.
//  - Explicit 2-stage register prefetch in the j-loop: stage for step i+1
//    is in flight while step i is consumed.
//  - LDS combine of 4 j-quarter partials (48 KB), fused epilogue unchanged.

#define BB 2
#define NN 2048
#define FF 128
#define HH 4
#define CC 64
#define HC 256
#define TN 8      // node rows per block, K1
#define LOG2E 1.4426950408889634f

typedef __attribute__((ext_vector_type(8))) short short8;
typedef __attribute__((ext_vector_type(4))) float f32x4;

__device__ __forceinline__ float wave_sum(float v) {
#pragma unroll
    for (int m = 32; m >= 1; m >>= 1) v += __shfl_xor(v, m, 64);
    return v;
}

__device__ __forceinline__ unsigned short bf16rne(float x) {
    unsigned u = __float_as_uint(x);
    return (unsigned short)((u + 0x7fffu + ((u >> 16) & 1u)) >> 16);
}

// ---------------- K1 ----------------
__global__ __launch_bounds__(256) void k1_proj(
    const float* __restrict__ X, const float* __restrict__ Wg,
    const float* __restrict__ a_src, const float* __restrict__ a_dst,
    unsigned short* __restrict__ hT, float* __restrict__ ssT,
    float* __restrict__ sdT)
{
    __shared__ float sX[TN][FF];
    const int blk = blockIdx.x;               // B*N/TN blocks
    const int b  = blk / (NN / TN);
    const int n0 = (blk % (NN / TN)) * TN;
    const int tid = threadIdx.x;
    const int h = tid >> 6, c = tid & 63;

    for (int idx = tid; idx < TN * FF; idx += 256) {
        int r = idx >> 7, f = idx & 127;
        sX[r][f] = X[(size_t)(b * NN + n0 + r) * FF + f];
    }
    __syncthreads();

    float hv[TN];
#pragma unroll
    for (int r = 0; r < TN; ++r) hv[r] = 0.f;

#pragma unroll 4
    for (int f4 = 0; f4 < FF / 4; ++f4) {
        const int f = f4 * 4;
        const float w0 = Wg[(h * FF + f + 0) * CC + c];
        const float w1 = Wg[(h * FF + f + 1) * CC + c];
        const float w2 = Wg[(h * FF + f + 2) * CC + c];
        const float w3 = Wg[(h * FF + f + 3) * CC + c];
#pragma unroll
        for (int r = 0; r < TN; ++r) {
            float4 x4 = *(const float4*)&sX[r][f];
            hv[r] = fmaf(x4.x, w0, hv[r]);
            hv[r] = fmaf(x4.y, w1, hv[r]);
            hv[r] = fmaf(x4.z, w2, hv[r]);
            hv[r] = fmaf(x4.w, w3, hv[r]);
        }
    }

    // hT[b][h][c][n], 8 consecutive n per thread -> one 16B store
    union { short8 v; unsigned short u[8]; } pk;
#pragma unroll
    for (int r = 0; r < TN; ++r) pk.u[r] = bf16rne(hv[r]);
    *(short8*)&hT[((size_t)(b * HH + h) * CC + c) * NN + n0] = pk.v;

    const float as = a_src[tid];
    const float ad = a_dst[tid];
#pragma unroll
    for (int r = 0; r < TN; ++r) {
        const int n = n0 + r;
        float s1 = wave_sum(hv[r] * as);
        float s2 = wave_sum(hv[r] * ad);
        if (c == 0) {
            ssT[(b * HH + h) * NN + n] = s1 * LOG2E;
            sdT[(b * HH + h) * NN + n] = s2 * LOG2E;
        }
    }
}

// ---------------- K2 ----------------
struct Stage {
    float4 aa, ab;    // Adj, 8 floats
    float4 sda, sdb;  // sd,  8 floats
    short8 bfr[4];    // hT B-frags
};

__device__ __forceinline__ void load_stage(
    Stage& s, const float* adjp, const float* sdp,
    const unsigned short* const* hb, int js)
{
    s.aa  = *(const float4*)(adjp + js);
    s.ab  = *(const float4*)(adjp + js + 4);
    s.sda = *(const float4*)(sdp + js);
    s.sdb = *(const float4*)(sdp + js + 4);
#pragma unroll
    for (int ni = 0; ni < 4; ++ni) s.bfr[ni] = *(const short8*)(hb[ni] + js);
}

__device__ __forceinline__ void consume_stage(
    const Stage& s, float ss, float& lsum, f32x4* acc)
{
    const float sd[8] = {s.sda.x, s.sda.y, s.sda.z, s.sda.w,
                         s.sdb.x, s.sdb.y, s.sdb.z, s.sdb.w};
    const float av[8] = {s.aa.x, s.aa.y, s.aa.z, s.aa.w,
                         s.ab.x, s.ab.y, s.ab.z, s.ab.w};
    float p[8];
#pragma unroll
    for (int t = 0; t < 8; ++t) {
        float x = ss + sd[t];
        x = fmaxf(x, 0.2f * x);                 // leaky_relu (alpha=0.2)
        float pv = (av[t] == 0.f) ? 0.f : __builtin_amdgcn_exp2f(x);
        lsum += pv;
        p[t] = pv;
    }
    union { short8 v; __hip_bfloat162 h2[4]; } pk;
#pragma unroll
    for (int t = 0; t < 4; ++t)
        pk.h2[t] = __float22bfloat162_rn(make_float2(p[2 * t], p[2 * t + 1]));
#pragma unroll
    for (int ni = 0; ni < 4; ++ni)
        acc[ni] = __builtin_amdgcn_mfma_f32_16x16x32_bf16(pk.v, s.bfr[ni], acc[ni], 0, 0, 0);
}

__global__ __launch_bounds__(1024) void k2_attn(
    const float* __restrict__ Adj, const unsigned short* __restrict__ hT,
    const float* __restrict__ ssT, const float* __restrict__ sdT,
    const float* __restrict__ b_gat, const float* __restrict__ gamma,
    const float* __restrict__ beta, float* __restrict__ out)
{
    __shared__ float accs[3][16][HH][64];   // 48 KB; bank = lane%32 (2-way, free)
    __shared__ float lsumx[3][HH][16];
    __shared__ float red1s[HH][16], red2s[HH][16];

    const int blk = blockIdx.x;             // B * (N/16)
    const int b  = blk >> 7;
    const int i0 = (blk & 127) << 4;
    const int tid  = threadIdx.x;
    const int wave = tid >> 6;
    const int h  = wave & 3;
    const int jq = wave >> 2;               // j-quarter: 512 j's each
    const int l  = tid & 63;
    const int lr = l & 15;                  // A row / B,D col in tile
    const int lq = l >> 4;                  // quad

    const float ss = ssT[(b * HH + h) * NN + i0 + lr];

    f32x4 acc[4];
#pragma unroll
    for (int ni = 0; ni < 4; ++ni) acc[ni] = (f32x4){0.f, 0.f, 0.f, 0.f};
    float lsum = 0.f;

    const float* adjp = Adj + (size_t)(b * NN + i0 + lr) * NN + jq * 512 + lq * 8;
    const float* sdp  = sdT + (b * HH + h) * NN + jq * 512 + lq * 8;
    const unsigned short* hb[4];
#pragma unroll
    for (int ni = 0; ni < 4; ++ni)
        hb[ni] = hT + ((size_t)(b * HH + h) * CC + ni * 16 + lr) * NN + jq * 512 + lq * 8;

    // 16 steps of 32 j; 2-stage rotation, loads one full step ahead.
    Stage s0, s1;
    load_stage(s0, adjp, sdp, hb, 0);
#pragma unroll 2
    for (int it = 0; it < 16; it += 2) {
        load_stage(s1, adjp, sdp, hb, (it + 1) * 32);
        consume_stage(s0, ss, lsum, acc);
        if (it + 2 < 16) load_stage(s0, adjp, sdp, hb, (it + 2) * 32);
        consume_stage(s1, ss, lsum, acc);
    }

    // reduce lsum over quads: every lane holds row-lsum for row lr (this jq)
    lsum += __shfl_xor(lsum, 16, 64);
    lsum += __shfl_xor(lsum, 32, 64);

    if (jq > 0) {
        if (lq == 0) lsumx[jq - 1][h][lr] = lsum;
#pragma unroll
        for (int ni = 0; ni < 4; ++ni)
#pragma unroll
            for (int r = 0; r < 4; ++r)
                accs[jq - 1][ni * 4 + r][h][l] = acc[ni][r];
    }
    __syncthreads();

    if (jq == 0) {
        const float lcomb = lsum + lsumx[0][h][lr] + lsumx[1][h][lr] + lsumx[2][h][lr];
        float lrow[4];
#pragma unroll
        for (int r = 0; r < 4; ++r) lrow[r] = __shfl(lcomb, lq * 4 + r, 64);

        float bg[4];
#pragma unroll
        for (int ni = 0; ni < 4; ++ni) bg[ni] = b_gat[h * 64 + ni * 16 + lr];

        float vals[4][4];   // [ni][r]
        float s1[4] = {0.f, 0.f, 0.f, 0.f}, s2[4] = {0.f, 0.f, 0.f, 0.f};
#pragma unroll
        for (int ni = 0; ni < 4; ++ni)
#pragma unroll
            for (int r = 0; r < 4; ++r) {
                float a = acc[ni][r] + accs[0][ni * 4 + r][h][l]
                        + accs[1][ni * 4 + r][h][l] + accs[2][ni * 4 + r][h][l];
                float v = a / lrow[r] + bg[ni];
                v = (v > 0.f) ? v : (__expf(v) - 1.f);   // ELU
                vals[ni][r] = v;
                s1[r] += v;
                s2[r] += v * v;
            }
        // reduce over the 16 col-lanes (rows are per-quad)
#pragma unroll
        for (int m = 1; m <= 8; m <<= 1)
#pragma unroll
            for (int r = 0; r < 4; ++r) {
                s1[r] += __shfl_xor(s1[r], m, 64);
                s2[r] += __shfl_xor(s2[r], m, 64);
            }
        if (lr == 0)
#pragma unroll
            for (int r = 0; r < 4; ++r) {
                red1s[h][lq * 4 + r] = s1[r];
                red2s[h][lq * 4 + r] = s2[r];
            }
        __syncthreads();

        const float gm[4] = {gamma[h * 64 + lr], gamma[h * 64 + 16 + lr],
                             gamma[h * 64 + 32 + lr], gamma[h * 64 + 48 + lr]};
        const float bm[4] = {beta[h * 64 + lr], beta[h * 64 + 16 + lr],
                             beta[h * 64 + 32 + lr], beta[h * 64 + 48 + lr]};
#pragma unroll
        for (int r = 0; r < 4; ++r) {
            const int row = lq * 4 + r;
            float S1 = red1s[0][row] + red1s[1][row] + red1s[2][row] + red1s[3][row];
            float S2 = red2s[0][row] + red2s[1][row] + red2s[2][row] + red2s[3][row];
            float mu  = S1 * (1.f / HC);
            float var = S2 * (1.f / HC) - mu * mu;
            float inv = rsqrtf(var + 1e-3f);
            float* op = out + (size_t)(b * NN + i0 + row) * HC + h * 64 + lr;
#pragma unroll
            for (int ni = 0; ni < 4; ++ni)
                op[ni * 16] = (vals[ni][r] - mu) * inv * gm[ni] + bm[ni];
        }
    } else {
        __syncthreads();   // matched barrier for jq>0 waves
    }
}

extern "C" void kernel_launch(void* const* d_in, const int* in_sizes, int n_in,
                              void* d_out, int out_size, void* d_ws, size_t ws_size,
                              hipStream_t stream)
{
    const float* X     = (const float*)d_in[0];
    const float* Adj   = (const float*)d_in[1];
    // d_in[2..4] = E, W_edge, b_edge: unused (see header).
    const float* Wg    = (const float*)d_in[5];
    const float* a_src = (const float*)d_in[6];
    const float* a_dst = (const float*)d_in[7];
    const float* b_gat = (const float*)d_in[8];
    const float* gam   = (const float*)d_in[9];
    const float* bet   = (const float*)d_in[10];
    float* out = (float*)d_out;

    const size_t hT_elems = (size_t)BB * HH * CC * NN;   // ushort (2 MB)
    const size_t ss_elems = (size_t)BB * HH * NN;        // float

    unsigned short* hT = (unsigned short*)d_ws;
    float* ssT = (float*)(hT + hT_elems);
    float* sdT = ssT + ss_elems;

    k1_proj<<<BB * NN / TN, 256, 0, stream>>>(X, Wg, a_src, a_dst, hT, ssT, sdT);
    k2_attn<<<BB * (NN / 16), 1024, 0, stream>>>(Adj, hT, ssT, sdT, b_gat, gam, bet, out);
}